// Round 16
// baseline (79.782 us; speedup 1.0000x reference)
//
#include <hip/hip_runtime.h>
#include <hip/hip_bf16.h>

// Quantized 3x3 conv via int8 implicit GEMM — R15 structure with block
// M=256 (4 output rows, 512 thr / 8 waves): quarters the original per-CU
// barrier-step count (126 -> 31.5). The fixed ~1200cyc/step stage-drain tax
// is the dominant term; steps/CU is the proven lever (R13->R15: -26us).
// B=32, Cin=128, Cout=256, H=W=56, pad=1. M=(b,h,w64), N=256, K=9x128.
//
// (x-xz)(w-wz) = xi*wi + (128-wz)*xi,  xi=x-128 (int8), wi=w-128 (int8);
// acc = i8gemm + (128-wz)*S,  S = window-sum of xi (pads contribute 0).
//
// xpi8 blob per (b,hh), 8KB: byte(w,c) = w*128 + (c ^ ((w&7)<<4)).
// wti8 blob per (r,ch), 16KB: byte(n,kl) = (n&63)*256 +
//   (((n>>6)*64 + kl) ^ (((n&63)&7)<<4)), kl in [0,64).
// Swizzles are involutions; conv stages with global_load_lds (LINEAR dest)
// and reads with the same XOR (rule #21).
//
// conv: 512 thr / 8 waves (2m x 4n), block tile 256m(4 h-rows) x 256n;
// per-wave 128m x 64n transposed-D (acc[fn][fm]: row=cout, col=m) ->
// coalesced stores. A = 6 row-blobs (48KB) resident; B dbuf 2x16KB staged
// per step; 18 steps x 32 MFMA/wave. LDS ~81.5KB -> 1 block/CU (8 waves).

typedef __attribute__((ext_vector_type(4))) int   i32x4;
typedef __attribute__((ext_vector_type(4))) float f32x4;

#define WTI8_BYTES (18 * 16384)            // 294,912
#define XPI8_BYTES (32 * 58 * 8192)        // 15,204,352

__device__ __forceinline__ void gload_lds16(const void* g, void* l) {
    __builtin_amdgcn_global_load_lds(
        (const __attribute__((address_space(1))) void*)g,
        (__attribute__((address_space(3))) void*)l, 16, 0, 0);
}

// ---- weight prep: w[cout][cin][3][3] - 128 -> wti8 blobs (swizzle-baked) ----
__global__ void wprep_kernel(const float* __restrict__ w, char* __restrict__ wt) {
    int cidx = blockIdx.x * 256 + threadIdx.x;   // 16B chunk id, < 18432
    int blob = cidx >> 10;                       // r*2 + ch
    int e    = cidx & 1023;
    int byte0 = e * 16;
    int rr  = byte0 >> 8;                        // row 0..63
    int off = byte0 & 255;                       // 16-aligned
    int src = off ^ ((rr & 7) << 4);             // un-swizzle (16B-block safe)
    int q   = src >> 6;                          // n>>6
    int kl0 = src & 63;                          // 16-aligned
    int r = blob >> 1, ch = blob & 1;
    int n = q * 64 + rr;
    union { char c[16]; i32x4 v; } u;
#pragma unroll
    for (int j = 0; j < 16; ++j) {
        int cin = ch * 64 + kl0 + j;
        u.c[j] = (char)((int)w[(size_t)n * 1152 + cin * 9 + r] - 128);
    }
    *(i32x4*)(wt + (size_t)blob * 16384 + byte0) = u.v;
}

// ---- x prep: coalesced NCHW read -> swizzled padded NHWC int8 + colsum ----
__global__ void xprep_kernel(const float* __restrict__ x, const float* __restrict__ xzp,
                             char* __restrict__ xpi8, int* __restrict__ colsum) {
    int bhh = blockIdx.x;                        // b*58 + hh
    int b = bhh / 58, hh = bhh % 58;
    int tid = threadIdx.x;
    char* blob = xpi8 + (size_t)bhh * 8192;
    int w  = tid & 63;                           // padded col (lane = w: coalesced)
    int cq = tid >> 6;                           // 0..3, 32 cin each
    __shared__ int ps[4][64];
    if (hh == 0 || hh == 57) {
        i32x4 z = {0, 0, 0, 0};
        *(i32x4*)(blob + tid * 32)      = z;
        *(i32x4*)(blob + tid * 32 + 16) = z;
        if (cq == 0) colsum[bhh * 64 + w] = 0;
        return;
    }
    const int ZX = (int)rintf(*xzp);             // 128
    bool valid = (w >= 1 && w <= 56);
    const float* xb = x + (size_t)b * 128 * 3136 + (size_t)(hh - 1) * 56 +
                      (valid ? (w - 1) : 0);
    int csum = 0;
#pragma unroll
    for (int u = 0; u < 2; ++u) {
        union { char c[16]; i32x4 v; } uu;
#pragma unroll
        for (int j = 0; j < 16; ++j) {
            int c = cq * 32 + u * 16 + j;
            int val = valid ? ((int)xb[(size_t)c * 3136] - ZX) : 0;
            uu.c[j] = (char)val;
            csum += val;
        }
        *(i32x4*)(blob + w * 128 + ((cq * 32 + u * 16) ^ ((w & 7) << 4))) = uu.v;
    }
    ps[cq][w] = csum;
    __syncthreads();
    if (cq == 0)
        colsum[bhh * 64 + w] = ps[0][w] + ps[1][w] + ps[2][w] + ps[3][w];
}

// ---- main conv: int8 implicit GEMM, 4 h-rows/block, transposed-D ----
__global__ __launch_bounds__(512, 2)
void conv_kernel(const char* __restrict__ wt,
                 const char* __restrict__ xpi8,
                 const int* __restrict__ colsum,
                 const float* __restrict__ bias,
                 const float* __restrict__ Mp,
                 const float* __restrict__ wzp,
                 const float* __restrict__ yzp,
                 float* __restrict__ out) {
    __shared__ __align__(1024) char smem[81920];   // A 48KB + B dbuf 2x16KB
    __shared__ int s2row[4][64];
    char* As = smem;
    char* Bs = smem + 49152;

    const int tid = threadIdx.x;
    const int lane = tid & 63;
    const int wid = tid >> 6;                      // 0..7
    const int wm = wid >> 2;                       // 0..1: h-row pair
    const int wn = wid & 3;                        // 0..3: 64-cout slice
    const int l15 = lane & 15, lg = lane >> 4;
    const int bx = blockIdx.x;                     // b*14 + h-group
    const int b = bx / 14;
    const int h0 = (bx % 14) * 4;                  // 4 output rows per block

    // ---- prologue: A = 6 row-blobs (48KB); B stage 0 (16KB); S2 rows ----
    const char* agbase = xpi8 + (size_t)(b * 58 + h0) * 8192;
#pragma unroll
    for (int i = 0; i < 6; ++i)
        gload_lds16(agbase + i * 8192 + tid * 16, As + i * 8192 + tid * 16);
#pragma unroll
    for (int i = 0; i < 2; ++i)
        gload_lds16(wt + i * 8192 + tid * 16, Bs + i * 8192 + tid * 16);
    if (tid < 256) {
        int row = tid >> 6, m = tid & 63;
        int s = 0;
        if (m < 56) {
#pragma unroll
            for (int kh = 0; kh < 3; ++kh)
#pragma unroll
                for (int kw = 0; kw < 3; ++kw)
                    s += colsum[(b * 58 + h0 + row + kh) * 64 + m + kw];
        }
        s2row[row][m] = s;
    }

    i32x4 acc[4][8];                               // [fn][fm]: row=cout, col=m
#pragma unroll
    for (int i = 0; i < 4; ++i)
#pragma unroll
        for (int j = 0; j < 8; ++j)
            acc[i][j] = (i32x4){0, 0, 0, 0};

    __syncthreads();                               // A + B0 + s2row ready

#pragma unroll
    for (int s = 0; s < 18; ++s) {                 // 9 taps x 2 cin-halves
        // prefetch next B blob into the other slot (issue-early, proven)
        if (s < 17) {
            const char* src = wt + (size_t)(s + 1) * 16384;
            char* dst = Bs + ((s + 1) & 1) * 16384;
#pragma unroll
            for (int i = 0; i < 2; ++i)
                gload_lds16(src + i * 8192 + tid * 16, dst + i * 8192 + tid * 16);
        }
        const int kh = (s >> 1) / 3, kw = (s >> 1) % 3, ch = s & 1;
        // B fragments (w): free = l15, k-chunk = lg
        i32x4 bfr[4];
#pragma unroll
        for (int fn = 0; fn < 4; ++fn) {
            int rr = fn * 16 + l15;
            int bb = (s & 1) * 16384 + rr * 256 +
                     ((wn * 64 + lg * 16) ^ ((rr & 7) << 4));
            bfr[fn] = *(const i32x4*)(Bs + bb);
        }
        // A fragments: 8 = 2 h-rows x 4 w-quarters (kw-shifted, swizzled)
        i32x4 afr[8];
#pragma unroll
        for (int fm = 0; fm < 8; ++fm) {
            int rowoff = fm >> 2;                  // 0..1 within wave's pair
            int wv = (fm & 3) * 16 + l15 + kw;
            int wc = wv > 63 ? 63 : wv;            // clamped lanes are dead outputs
            int ab = (wm * 2 + rowoff + kh) * 8192 + wc * 128 +
                     ((ch * 64 + lg * 16) ^ ((wc & 7) << 4));
            afr[fm] = *(const i32x4*)(As + ab);
        }
        // swapped operands: D[row=cout][col=m]
#pragma unroll
        for (int fn = 0; fn < 4; ++fn)
#pragma unroll
            for (int fm = 0; fm < 8; ++fm)
                acc[fn][fm] = __builtin_amdgcn_mfma_i32_16x16x64_i8(
                    bfr[fn], afr[fm], acc[fn][fm], 0, 0, 0);
        __syncthreads();                           // drain prefetch + WAR guard
    }

    // ---- epilogue: +correction, requantize, ReLU, round; coalesced in m ----
    const float Mv  = *Mp;
    const float yzv = *yzp;
    const float CWf = 128.0f - *wzp;               // (128 - w_zero)
#pragma unroll
    for (int fn = 0; fn < 4; ++fn) {
#pragma unroll
        for (int reg = 0; reg < 4; ++reg) {
            const int cout = wn * 64 + fn * 16 + lg * 4 + reg;
            const float bv = bias[cout];
#pragma unroll
            for (int fm = 0; fm < 8; ++fm) {
                const int row = wm * 2 + (fm >> 2);
                const int m = (fm & 3) * 16 + l15; // lane-contiguous
                if (m < 56) {
                    const size_t rowb =
                        ((size_t)(b * 256 + cout) * 56 + h0 + row) * 56;
                    float af = (float)acc[fn][fm][reg] +
                               CWf * (float)s2row[row][m];
                    float v = (af + bv) * Mv + yzv;
                    v = fmaxf(v, yzv);
                    out[rowb + m] = rintf(v);
                }
            }
        }
    }
}

extern "C" void kernel_launch(void* const* d_in, const int* in_sizes, int n_in,
                              void* d_out, int out_size, void* d_ws, size_t ws_size,
                              hipStream_t stream) {
    const float* x    = (const float*)d_in[0];
    const float* w    = (const float*)d_in[1];
    const float* bias = (const float*)d_in[2];
    const float* Mp   = (const float*)d_in[3];
    const float* xzp  = (const float*)d_in[4];
    const float* wzp  = (const float*)d_in[5];
    const float* yzp  = (const float*)d_in[6];
    float* out = (float*)d_out;

    char* wt     = (char*)d_ws;                          // 288 KB
    char* xpi8   = wt + WTI8_BYTES;                      // 15.2 MB
    int*  colsum = (int*)(xpi8 + XPI8_BYTES);            // 475 KB

    wprep_kernel<<<72, 256, 0, stream>>>(w, wt);
    xprep_kernel<<<32 * 58, 256, 0, stream>>>(x, xzp, xpi8, colsum);
    conv_kernel<<<32 * 14, 512, 0, stream>>>(wt, xpi8, colsum, bias, Mp, wzp, yzp, out);
}

// Round 17
// 76.148 us; speedup vs baseline: 1.0477x; 1.0477x over previous
//
#include <hip/hip_runtime.h>
#include <hip/hip_bf16.h>

// Quantized 3x3 conv via int8 implicit GEMM — wave-private B staging with
// counted per-wave vmcnt; ZERO in-loop barriers (kills the 8-wave convoy
// that serialized MFMA/LDS/stage pipes in R13-R16).
// B=32, Cin=128, Cout=256, H=W=56, pad=1. M=(b,h,w64), N=256, K=9x128.
//
// (x-xz)(w-wz) = xi*wi + (128-wz)*xi,  xi=x-128 (int8), wi=w-128 (int8);
// acc = i8gemm + (128-wz)*S,  S = window-sum of xi (pads contribute 0).
//
// xpi8 blob per (b,hh), 8KB: byte(w,c) = w*128 + (c ^ ((w&7)<<4)).
// wt layout: per (s=r*2+ch, wn) a 4KB panel of 64 rows x 64B:
//   byte(nn, kl) = nn*64 + (kl ^ ((nn&3)<<4)),  n = wn*64+nn, cin = ch*64+kl.
// Involution swizzles; staged linearly by global_load_lds, read with the
// same XOR (rule #21).
//
// conv: 512 thr / 8 waves (2m x 4n), block tile 256m(4 h-rows) x 256n;
// per-wave 128m x 64n transposed-D. A = 48KB shared, resident (1 prologue
// barrier). B = per-wave 3-slot ring (3x4KB x 8 waves = 96KB): wave stages
// its own panel (4 x global_load_lds), waits s_waitcnt vmcnt(8) — per-wave
// counter, no cross-wave sync. Slot (s+2)%3 was read at iter s-1 -> 2-iter
// WAR gap. Waves drift freely; pipes overlap across waves per SIMD.

typedef __attribute__((ext_vector_type(4))) int   i32x4;
typedef __attribute__((ext_vector_type(4))) float f32x4;

#define WTI8_BYTES (18 * 16384)            // 294,912
#define XPI8_BYTES (32 * 58 * 8192)        // 15,204,352

__device__ __forceinline__ void gload_lds16(const void* g, void* l) {
    __builtin_amdgcn_global_load_lds(
        (const __attribute__((address_space(1))) void*)g,
        (__attribute__((address_space(3))) void*)l, 16, 0, 0);
}

// ---- weight prep: w[cout][cin][3][3] - 128 -> per-(s,wn) 4KB panels ----
__global__ void wprep_kernel(const float* __restrict__ w, char* __restrict__ wt) {
    int cidx = blockIdx.x * 256 + threadIdx.x;   // 16B chunk id, < 18432
    int byte0 = cidx * 16;
    int s    = byte0 >> 14;                      // 0..17
    int wn   = (byte0 >> 12) & 3;
    int e4   = byte0 & 4095;
    int nn   = e4 >> 6;                          // row 0..63
    int koff = e4 & 63;                          // 16-aligned
    int kl   = koff ^ ((nn & 3) << 4);           // un-swizzle (16-aligned)
    int n = wn * 64 + nn;
    int r = s >> 1, ch = s & 1;
    union { char c[16]; i32x4 v; } u;
#pragma unroll
    for (int j = 0; j < 16; ++j) {
        int cin = ch * 64 + kl + j;
        u.c[j] = (char)((int)w[(size_t)n * 1152 + cin * 9 + r] - 128);
    }
    *(i32x4*)(wt + byte0) = u.v;
}

// ---- x prep: coalesced NCHW read -> swizzled padded NHWC int8 + colsum ----
__global__ void xprep_kernel(const float* __restrict__ x, const float* __restrict__ xzp,
                             char* __restrict__ xpi8, int* __restrict__ colsum) {
    int bhh = blockIdx.x;                        // b*58 + hh
    int b = bhh / 58, hh = bhh % 58;
    int tid = threadIdx.x;
    char* blob = xpi8 + (size_t)bhh * 8192;
    int w  = tid & 63;                           // padded col (lane = w: coalesced)
    int cq = tid >> 6;                           // 0..3, 32 cin each
    __shared__ int ps[4][64];
    if (hh == 0 || hh == 57) {
        i32x4 z = {0, 0, 0, 0};
        *(i32x4*)(blob + tid * 32)      = z;
        *(i32x4*)(blob + tid * 32 + 16) = z;
        if (cq == 0) colsum[bhh * 64 + w] = 0;
        return;
    }
    const int ZX = (int)rintf(*xzp);             // 128
    bool valid = (w >= 1 && w <= 56);
    const float* xb = x + (size_t)b * 128 * 3136 + (size_t)(hh - 1) * 56 +
                      (valid ? (w - 1) : 0);
    int csum = 0;
#pragma unroll
    for (int u = 0; u < 2; ++u) {
        union { char c[16]; i32x4 v; } uu;
#pragma unroll
        for (int j = 0; j < 16; ++j) {
            int c = cq * 32 + u * 16 + j;
            int val = valid ? ((int)xb[(size_t)c * 3136] - ZX) : 0;
            uu.c[j] = (char)val;
            csum += val;
        }
        *(i32x4*)(blob + w * 128 + ((cq * 32 + u * 16) ^ ((w & 7) << 4))) = uu.v;
    }
    ps[cq][w] = csum;
    __syncthreads();
    if (cq == 0)
        colsum[bhh * 64 + w] = ps[0][w] + ps[1][w] + ps[2][w] + ps[3][w];
}

// ---- main conv: barrier-free K-loop, wave-private B ring, transposed-D ----
__global__ __launch_bounds__(512, 1)
void conv_kernel(const char* __restrict__ wt,
                 const char* __restrict__ xpi8,
                 const int* __restrict__ colsum,
                 const float* __restrict__ bias,
                 const float* __restrict__ Mp,
                 const float* __restrict__ wzp,
                 const float* __restrict__ yzp,
                 float* __restrict__ out) {
    __shared__ __align__(1024) char As[49152];     // A: 6 row-blobs, shared
    __shared__ __align__(1024) char Bp[98304];     // 8 waves x 3 slots x 4KB
    __shared__ int s2row[4][64];

    const int tid = threadIdx.x;
    const int lane = tid & 63;
    const int wid = tid >> 6;                      // 0..7
    const int wm = wid >> 2;                       // 0..1: h-row pair
    const int wn = wid & 3;                        // 0..3: 64-cout slice
    const int l15 = lane & 15, lg = lane >> 4;
    const int bx = blockIdx.x;                     // b*14 + h-group
    const int b = bx / 14;
    const int h0 = (bx % 14) * 4;                  // 4 output rows per block

    char* bpriv = Bp + wid * 12288;                // this wave's 3-slot ring
    const char* bwsrc = wt + wn * 4096 + lane * 16;

    // ---- prologue: A (48KB); B s=0,1 into slots 0,1; S2 rows ----
    const char* agbase = xpi8 + (size_t)(b * 58 + h0) * 8192;
#pragma unroll
    for (int i = 0; i < 6; ++i)
        gload_lds16(agbase + i * 8192 + tid * 16, As + i * 8192 + tid * 16);
#pragma unroll
    for (int st = 0; st < 2; ++st)
#pragma unroll
        for (int i = 0; i < 4; ++i)
            gload_lds16(bwsrc + (size_t)st * 16384 + i * 1024,
                        bpriv + st * 4096 + i * 1024 + lane * 16);
    if (tid < 256) {
        int row = tid >> 6, m = tid & 63;
        int s = 0;
        if (m < 56) {
#pragma unroll
            for (int kh = 0; kh < 3; ++kh)
#pragma unroll
                for (int kw = 0; kw < 3; ++kw)
                    s += colsum[(b * 58 + h0 + row + kh) * 64 + m + kw];
        }
        s2row[row][m] = s;
    }

    i32x4 acc[4][8];                               // [fn][fm]: row=cout, col=m
#pragma unroll
    for (int i = 0; i < 4; ++i)
#pragma unroll
        for (int j = 0; j < 8; ++j)
            acc[i][j] = (i32x4){0, 0, 0, 0};

    __syncthreads();                               // the ONLY barrier (A+s2row)

#pragma unroll
    for (int s = 0; s < 18; ++s) {                 // 9 taps x 2 cin-halves
        // issue stage s+2 into private slot (s+2)%3 (read 2 iters ago)
        if (s < 16) {
#pragma unroll
            for (int i = 0; i < 4; ++i)
                gload_lds16(bwsrc + (size_t)(s + 2) * 16384 + i * 1024,
                            bpriv + ((s + 2) % 3) * 4096 + i * 1024 + lane * 16);
        }
        // per-wave counted wait: slot s%3's 4 loads complete
        if (s < 16)      asm volatile("s_waitcnt vmcnt(8)" ::: "memory");
        else if (s == 16) asm volatile("s_waitcnt vmcnt(4)" ::: "memory");
        else              asm volatile("s_waitcnt vmcnt(0)" ::: "memory");
        __builtin_amdgcn_sched_barrier(0);

        const int kh = (s >> 1) / 3, kw = (s >> 1) % 3, ch = s & 1;
        const char* bslot = bpriv + (s % 3) * 4096;
        // B fragments from private slot (4-way XOR layout)
        i32x4 bfr[4];
#pragma unroll
        for (int fn = 0; fn < 4; ++fn) {
            int nn = fn * 16 + l15;
            bfr[fn] = *(const i32x4*)(bslot + nn * 64 +
                                      ((lg * 16) ^ ((l15 & 3) << 4)));
        }
        // A fragments: 8 = 2 h-rows x 4 w-quarters (kw-shifted, swizzled)
        i32x4 afr[8];
#pragma unroll
        for (int fm = 0; fm < 8; ++fm) {
            int rowoff = fm >> 2;
            int wv = (fm & 3) * 16 + l15 + kw;
            int wc = wv > 63 ? 63 : wv;            // clamped lanes are dead outputs
            int ab = (wm * 2 + rowoff + kh) * 8192 + wc * 128 +
                     ((ch * 64 + lg * 16) ^ ((wc & 7) << 4));
            afr[fm] = *(const i32x4*)(As + ab);
        }
        // swapped operands: D[row=cout][col=m]
#pragma unroll
        for (int fn = 0; fn < 4; ++fn)
#pragma unroll
            for (int fm = 0; fm < 8; ++fm)
                acc[fn][fm] = __builtin_amdgcn_mfma_i32_16x16x64_i8(
                    bfr[fn], afr[fm], acc[fn][fm], 0, 0, 0);
    }

    // ---- epilogue: +correction, requantize, ReLU, round; coalesced in m ----
    const float Mv  = *Mp;
    const float yzv = *yzp;
    const float CWf = 128.0f - *wzp;               // (128 - w_zero)
#pragma unroll
    for (int fn = 0; fn < 4; ++fn) {
#pragma unroll
        for (int reg = 0; reg < 4; ++reg) {
            const int cout = wn * 64 + fn * 16 + lg * 4 + reg;
            const float bv = bias[cout];
#pragma unroll
            for (int fm = 0; fm < 8; ++fm) {
                const int row = wm * 2 + (fm >> 2);
                const int m = (fm & 3) * 16 + l15; // lane-contiguous
                if (m < 56) {
                    const size_t rowb =
                        ((size_t)(b * 256 + cout) * 56 + h0 + row) * 56;
                    float af = (float)acc[fn][fm][reg] +
                               CWf * (float)s2row[row][m];
                    float v = (af + bv) * Mv + yzv;
                    v = fmaxf(v, yzv);
                    out[rowb + m] = rintf(v);
                }
            }
        }
    }
}

extern "C" void kernel_launch(void* const* d_in, const int* in_sizes, int n_in,
                              void* d_out, int out_size, void* d_ws, size_t ws_size,
                              hipStream_t stream) {
    const float* x    = (const float*)d_in[0];
    const float* w    = (const float*)d_in[1];
    const float* bias = (const float*)d_in[2];
    const float* Mp   = (const float*)d_in[3];
    const float* xzp  = (const float*)d_in[4];
    const float* wzp  = (const float*)d_in[5];
    const float* yzp  = (const float*)d_in[6];
    float* out = (float*)d_out;

    char* wt     = (char*)d_ws;                          // 288 KB
    char* xpi8   = wt + WTI8_BYTES;                      // 15.2 MB
    int*  colsum = (int*)(xpi8 + XPI8_BYTES);            // 475 KB

    wprep_kernel<<<72, 256, 0, stream>>>(w, wt);
    xprep_kernel<<<32 * 58, 256, 0, stream>>>(x, xzp, xpi8, colsum);
    conv_kernel<<<32 * 14, 512, 0, stream>>>(wt, xpi8, colsum, bias, Mp, wzp, yzp, out);
}

// Round 19
// 75.796 us; speedup vs baseline: 1.0526x; 1.0046x over previous
//
#include <hip/hip_runtime.h>
#include <hip/hip_bf16.h>

// Quantized 3x3 conv via int8 implicit GEMM — wave-private B staging ring
// + register-parity-pipelined B fragments (vmcnt-gated reads moved one full
// step ahead of use). Zero in-loop barriers.
// B=32, Cin=128, Cout=256, H=W=56, pad=1. M=(b,h,w64), N=256, K=9x128.
//
// (x-xz)(w-wz) = xi*wi + (128-wz)*xi,  xi=x-128 (int8), wi=w-128 (int8);
// acc = i8gemm + (128-wz)*S,  S = window-sum of xi (pads contribute 0).
//
// xpi8 blob per (b,hh), 8KB: byte(w,c) = w*128 + (c ^ ((w&7)<<4)).
// wt layout: per (s=r*2+ch, wn) a 4KB panel of 64 rows x 64B:
//   byte(nn, kl) = nn*64 + (kl ^ ((nn&3)<<4)),  n = wn*64+nn, cin = ch*64+kl.
// Involution swizzles; staged linearly by global_load_lds, read with the
// same XOR (rule #21).
//
// Step s (full unroll, all indices static):
//   issue gload s+2 -> slot (s+2)%3          (never drains: counted vmcnt)
//   s<16: vmcnt(4)  [slot s+1 landed; s+2 in flight]   s==16: vmcnt(0)
//   read bfr[(s+1)&1] from slot (s+1)%3      (for NEXT step - full slack)
//   read afr (current, A resident in LDS)
//   32 MFMA on bfr[s&1] (register operands, no wait)

typedef __attribute__((ext_vector_type(4))) int   i32x4;
typedef __attribute__((ext_vector_type(4))) float f32x4;

#define WTI8_BYTES (18 * 16384)            // 294,912
#define XPI8_BYTES (32 * 58 * 8192)        // 15,204,352

__device__ __forceinline__ void gload_lds16(const void* g, void* l) {
    __builtin_amdgcn_global_load_lds(
        (const __attribute__((address_space(1))) void*)g,
        (__attribute__((address_space(3))) void*)l, 16, 0, 0);
}

// ---- weight prep: w[cout][cin][3][3] - 128 -> per-(s,wn) 4KB panels ----
__global__ void wprep_kernel(const float* __restrict__ w, char* __restrict__ wt) {
    int cidx = blockIdx.x * 256 + threadIdx.x;   // 16B chunk id, < 18432
    int byte0 = cidx * 16;
    int s    = byte0 >> 14;                      // 0..17
    int wn   = (byte0 >> 12) & 3;
    int e4   = byte0 & 4095;
    int nn   = e4 >> 6;                          // row 0..63
    int koff = e4 & 63;                          // 16-aligned
    int kl   = koff ^ ((nn & 3) << 4);           // un-swizzle (16-aligned)
    int n = wn * 64 + nn;
    int r = s >> 1, ch = s & 1;
    union { char c[16]; i32x4 v; } u;
#pragma unroll
    for (int j = 0; j < 16; ++j) {
        int cin = ch * 64 + kl + j;
        u.c[j] = (char)((int)w[(size_t)n * 1152 + cin * 9 + r] - 128);
    }
    *(i32x4*)(wt + byte0) = u.v;
}

// ---- x prep: coalesced NCHW read -> swizzled padded NHWC int8 + colsum ----
__global__ void xprep_kernel(const float* __restrict__ x, const float* __restrict__ xzp,
                             char* __restrict__ xpi8, int* __restrict__ colsum) {
    int bhh = blockIdx.x;                        // b*58 + hh
    int b = bhh / 58, hh = bhh % 58;
    int tid = threadIdx.x;
    char* blob = xpi8 + (size_t)bhh * 8192;
    int w  = tid & 63;                           // padded col (lane = w: coalesced)
    int cq = tid >> 6;                           // 0..3, 32 cin each
    __shared__ int ps[4][64];
    if (hh == 0 || hh == 57) {
        i32x4 z = {0, 0, 0, 0};
        *(i32x4*)(blob + tid * 32)      = z;
        *(i32x4*)(blob + tid * 32 + 16) = z;
        if (cq == 0) colsum[bhh * 64 + w] = 0;
        return;
    }
    const int ZX = (int)rintf(*xzp);             // 128
    bool valid = (w >= 1 && w <= 56);
    const float* xb = x + (size_t)b * 128 * 3136 + (size_t)(hh - 1) * 56 +
                      (valid ? (w - 1) : 0);
    int csum = 0;
#pragma unroll
    for (int u = 0; u < 2; ++u) {
        union { char c[16]; i32x4 v; } uu;
#pragma unroll
        for (int j = 0; j < 16; ++j) {
            int c = cq * 32 + u * 16 + j;
            int val = valid ? ((int)xb[(size_t)c * 3136] - ZX) : 0;
            uu.c[j] = (char)val;
            csum += val;
        }
        *(i32x4*)(blob + w * 128 + ((cq * 32 + u * 16) ^ ((w & 7) << 4))) = uu.v;
    }
    ps[cq][w] = csum;
    __syncthreads();
    if (cq == 0)
        colsum[bhh * 64 + w] = ps[0][w] + ps[1][w] + ps[2][w] + ps[3][w];
}

// ---- main conv: barrier-free, wave-private ring, reg-pipelined B ----
__global__ __launch_bounds__(512, 1)
void conv_kernel(const char* __restrict__ wt,
                 const char* __restrict__ xpi8,
                 const int* __restrict__ colsum,
                 const float* __restrict__ bias,
                 const float* __restrict__ Mp,
                 const float* __restrict__ wzp,
                 const float* __restrict__ yzp,
                 float* __restrict__ out) {
    __shared__ __align__(1024) char As[49152];     // A: 6 row-blobs, shared
    __shared__ __align__(1024) char Bp[98304];     // 8 waves x 3 slots x 4KB
    __shared__ int s2row[4][64];

    const int tid = threadIdx.x;
    const int lane = tid & 63;
    const int wid = tid >> 6;                      // 0..7
    const int wm = wid >> 2;                       // 0..1: h-row pair
    const int wn = wid & 3;                        // 0..3: 64-cout slice
    const int l15 = lane & 15, lg = lane >> 4;
    const int bx = blockIdx.x;                     // b*14 + h-group
    const int b = bx / 14;
    const int h0 = (bx % 14) * 4;                  // 4 output rows per block

    char* bpriv = Bp + wid * 12288;                // this wave's 3-slot ring
    const char* bwsrc = wt + wn * 4096 + lane * 16;
    const int bfoff = (lg * 16) ^ ((l15 & 3) << 4);  // B frag byte within row

    // ---- prologue: A (48KB); B s=0,1 into slots 0,1; S2 rows ----
    const char* agbase = xpi8 + (size_t)(b * 58 + h0) * 8192;
#pragma unroll
    for (int i = 0; i < 6; ++i)
        gload_lds16(agbase + i * 8192 + tid * 16, As + i * 8192 + tid * 16);
#pragma unroll
    for (int st = 0; st < 2; ++st)
#pragma unroll
        for (int i = 0; i < 4; ++i)
            gload_lds16(bwsrc + (size_t)st * 16384 + i * 1024,
                        bpriv + st * 4096 + i * 1024 + lane * 16);
    if (tid < 256) {
        int row = tid >> 6, m = tid & 63;
        int s = 0;
        if (m < 56) {
#pragma unroll
            for (int kh = 0; kh < 3; ++kh)
#pragma unroll
                for (int kw = 0; kw < 3; ++kw)
                    s += colsum[(b * 58 + h0 + row + kh) * 64 + m + kw];
        }
        s2row[row][m] = s;
    }

    i32x4 acc[4][8];                               // [fn][fm]: row=cout, col=m
#pragma unroll
    for (int i = 0; i < 4; ++i)
#pragma unroll
        for (int j = 0; j < 8; ++j)
            acc[i][j] = (i32x4){0, 0, 0, 0};

    __syncthreads();                               // the ONLY barrier (drains all)

    // pre-read step-0 B fragments (slot 0 landed: barrier drained vmcnt)
    i32x4 bfr[2][4];
#pragma unroll
    for (int fn = 0; fn < 4; ++fn) {
        int nn = fn * 16 + l15;
        bfr[0][fn] = *(const i32x4*)(bpriv + nn * 64 + bfoff);
    }

#pragma unroll
    for (int s = 0; s < 18; ++s) {                 // 9 taps x 2 cin-halves
        // issue stage s+2 into private slot (s+2)%3
        if (s < 16) {
#pragma unroll
            for (int i = 0; i < 4; ++i)
                gload_lds16(bwsrc + (size_t)(s + 2) * 16384 + i * 1024,
                            bpriv + ((s + 2) % 3) * 4096 + i * 1024 + lane * 16);
        }
        // counted per-wave wait: slot s+1's loads landed (s+2 stays in flight)
        if (s < 16)       asm volatile("s_waitcnt vmcnt(4)" ::: "memory");
        else if (s == 16) asm volatile("s_waitcnt vmcnt(0)" ::: "memory");
        // read NEXT step's B fragments (consumed one full step later)
        if (s < 17) {
            const char* bslot = bpriv + ((s + 1) % 3) * 4096;
#pragma unroll
            for (int fn = 0; fn < 4; ++fn) {
                int nn = fn * 16 + l15;
                bfr[(s + 1) & 1][fn] = *(const i32x4*)(bslot + nn * 64 + bfoff);
            }
        }
        const int kh = (s >> 1) / 3, kw = (s >> 1) % 3, ch = s & 1;
        // A fragments (current step; A resident, no wait)
        i32x4 afr[8];
#pragma unroll
        for (int fm = 0; fm < 8; ++fm) {
            int rowoff = fm >> 2;
            int wv = (fm & 3) * 16 + l15 + kw;
            int wc = wv > 63 ? 63 : wv;            // clamped lanes are dead outputs
            int ab = (wm * 2 + rowoff + kh) * 8192 + wc * 128 +
                     ((ch * 64 + lg * 16) ^ ((wc & 7) << 4));
            afr[fm] = *(const i32x4*)(As + ab);
        }
        // swapped operands: D[row=cout][col=m]; B operand is register-resident
#pragma unroll
        for (int fn = 0; fn < 4; ++fn)
#pragma unroll
            for (int fm = 0; fm < 8; ++fm)
                acc[fn][fm] = __builtin_amdgcn_mfma_i32_16x16x64_i8(
                    bfr[s & 1][fn], afr[fm], acc[fn][fm], 0, 0, 0);
    }

    // ---- epilogue: +correction, requantize, ReLU, round; coalesced in m ----
    const float Mv  = *Mp;
    const float yzv = *yzp;
    const float CWf = 128.0f - *wzp;               // (128 - w_zero)
#pragma unroll
    for (int fn = 0; fn < 4; ++fn) {
#pragma unroll
        for (int reg = 0; reg < 4; ++reg) {
            const int cout = wn * 64 + fn * 16 + lg * 4 + reg;
            const float bv = bias[cout];
#pragma unroll
            for (int fm = 0; fm < 8; ++fm) {
                const int row = wm * 2 + (fm >> 2);
                const int m = (fm & 3) * 16 + l15; // lane-contiguous
                if (m < 56) {
                    const size_t rowb =
                        ((size_t)(b * 256 + cout) * 56 + h0 + row) * 56;
                    float af = (float)acc[fn][fm][reg] +
                               CWf * (float)s2row[row][m];
                    float v = (af + bv) * Mv + yzv;
                    v = fmaxf(v, yzv);
                    out[rowb + m] = rintf(v);
                }
            }
        }
    }
}

extern "C" void kernel_launch(void* const* d_in, const int* in_sizes, int n_in,
                              void* d_out, int out_size, void* d_ws, size_t ws_size,
                              hipStream_t stream) {
    const float* x    = (const float*)d_in[0];
    const float* w    = (const float*)d_in[1];
    const float* bias = (const float*)d_in[2];
    const float* Mp   = (const float*)d_in[3];
    const float* xzp  = (const float*)d_in[4];
    const float* wzp  = (const float*)d_in[5];
    const float* yzp  = (const float*)d_in[6];
    float* out = (float*)d_out;

    char* wt     = (char*)d_ws;                          // 288 KB
    char* xpi8   = wt + WTI8_BYTES;                      // 15.2 MB
    int*  colsum = (int*)(xpi8 + XPI8_BYTES);            // 475 KB

    wprep_kernel<<<72, 256, 0, stream>>>(w, wt);
    xprep_kernel<<<32 * 58, 256, 0, stream>>>(x, xzp, xpi8, colsum);
    conv_kernel<<<32 * 14, 512, 0, stream>>>(wt, xpi8, colsum, bias, Mp, wzp, yzp, out);
}

// Round 20
// 75.464 us; speedup vs baseline: 1.0572x; 1.0044x over previous
//
#include <hip/hip_runtime.h>
#include <hip/hip_bf16.h>

// Quantized 3x3 conv via int8 implicit GEMM — 2 co-resident blocks/CU so
// epilogue store bursts overlap the other block's compute (R19 accounting:
// ~40% of conv was the serialized per-block store burst at 1 block/CU).
// Wave-private 2-slot B ring, counted per-wave vmcnt, zero in-loop barriers.
// B=32, Cin=128, Cout=256, H=W=56, pad=1. M=(b,h,w64), N=256, K=9x128.
//
// (x-xz)(w-wz) = xi*wi + (128-wz)*xi,  xi=x-128 (int8), wi=w-128 (int8);
// acc = i8gemm + (128-wz)*S,  S = window-sum of xi (pads contribute 0).
//
// xpi8 blob per (b,hh), 8KB: byte(w,c) = w*128 + (c ^ ((w&7)<<4)).
// wt layout: per (s=r*2+ch, wn) a 4KB panel of 64 rows x 64B:
//   byte(nn, kl) = nn*64 + (kl ^ ((nn&3)<<4)),  n = wn*64+nn, cin = ch*64+kl.
// Involution swizzles; staged linearly by global_load_lds, read with the
// same XOR (rule #21).
//
// conv: 256 thr / 4 waves (wn=wid), block tile 128m(2 h-rows) x 256n;
// per-wave 128m x 64n transposed-D. LDS = A 32KB + B 4x8KB + s2row ~= 64.7KB
// -> 2 blocks/CU resident; grid 896 -> 3.5 phase-drifted rounds/CU.
// Step s: read frags (stage s resident) -> lgkmcnt(0) frees slot s&1 ->
// issue stage s+2 into it -> vmcnt(4) [stage s+1 landed, 1-step slack] ->
// 32 MFMA. vmcnt never drains mid-loop.

typedef __attribute__((ext_vector_type(4))) int   i32x4;
typedef __attribute__((ext_vector_type(4))) float f32x4;

#define WTI8_BYTES (18 * 16384)            // 294,912
#define XPI8_BYTES (32 * 58 * 8192)        // 15,204,352

__device__ __forceinline__ void gload_lds16(const void* g, void* l) {
    __builtin_amdgcn_global_load_lds(
        (const __attribute__((address_space(1))) void*)g,
        (__attribute__((address_space(3))) void*)l, 16, 0, 0);
}

// ---- weight prep: w[cout][cin][3][3] - 128 -> per-(s,wn) 4KB panels ----
__global__ void wprep_kernel(const float* __restrict__ w, char* __restrict__ wt) {
    int cidx = blockIdx.x * 256 + threadIdx.x;   // 16B chunk id, < 18432
    int byte0 = cidx * 16;
    int s    = byte0 >> 14;                      // 0..17
    int wn   = (byte0 >> 12) & 3;
    int e4   = byte0 & 4095;
    int nn   = e4 >> 6;                          // row 0..63
    int koff = e4 & 63;                          // 16-aligned
    int kl   = koff ^ ((nn & 3) << 4);           // un-swizzle (16-aligned)
    int n = wn * 64 + nn;
    int r = s >> 1, ch = s & 1;
    union { char c[16]; i32x4 v; } u;
#pragma unroll
    for (int j = 0; j < 16; ++j) {
        int cin = ch * 64 + kl + j;
        u.c[j] = (char)((int)w[(size_t)n * 1152 + cin * 9 + r] - 128);
    }
    *(i32x4*)(wt + byte0) = u.v;
}

// ---- x prep: coalesced NCHW read -> swizzled padded NHWC int8 + colsum ----
__global__ void xprep_kernel(const float* __restrict__ x, const float* __restrict__ xzp,
                             char* __restrict__ xpi8, int* __restrict__ colsum) {
    int bhh = blockIdx.x;                        // b*58 + hh
    int b = bhh / 58, hh = bhh % 58;
    int tid = threadIdx.x;
    char* blob = xpi8 + (size_t)bhh * 8192;
    int w  = tid & 63;                           // padded col (lane = w: coalesced)
    int cq = tid >> 6;                           // 0..3, 32 cin each
    __shared__ int ps[4][64];
    if (hh == 0 || hh == 57) {
        i32x4 z = {0, 0, 0, 0};
        *(i32x4*)(blob + tid * 32)      = z;
        *(i32x4*)(blob + tid * 32 + 16) = z;
        if (cq == 0) colsum[bhh * 64 + w] = 0;
        return;
    }
    const int ZX = (int)rintf(*xzp);             // 128
    bool valid = (w >= 1 && w <= 56);
    const float* xb = x + (size_t)b * 128 * 3136 + (size_t)(hh - 1) * 56 +
                      (valid ? (w - 1) : 0);
    int csum = 0;
#pragma unroll
    for (int u = 0; u < 2; ++u) {
        union { char c[16]; i32x4 v; } uu;
#pragma unroll
        for (int j = 0; j < 16; ++j) {
            int c = cq * 32 + u * 16 + j;
            int val = valid ? ((int)xb[(size_t)c * 3136] - ZX) : 0;
            uu.c[j] = (char)val;
            csum += val;
        }
        *(i32x4*)(blob + w * 128 + ((cq * 32 + u * 16) ^ ((w & 7) << 4))) = uu.v;
    }
    ps[cq][w] = csum;
    __syncthreads();
    if (cq == 0)
        colsum[bhh * 64 + w] = ps[0][w] + ps[1][w] + ps[2][w] + ps[3][w];
}

// ---- main conv: 2 blocks/CU, wave-private 2-slot ring, transposed-D ----
__global__ __launch_bounds__(256, 2)
void conv_kernel(const char* __restrict__ wt,
                 const char* __restrict__ xpi8,
                 const int* __restrict__ colsum,
                 const float* __restrict__ bias,
                 const float* __restrict__ Mp,
                 const float* __restrict__ wzp,
                 const float* __restrict__ yzp,
                 float* __restrict__ out) {
    __shared__ __align__(1024) char As[32768];     // A: 4 row-blobs, shared
    __shared__ __align__(1024) char Bp[32768];     // 4 waves x 2 slots x 4KB
    __shared__ int s2row[2][64];

    const int tid = threadIdx.x;
    const int lane = tid & 63;
    const int wn = tid >> 6;                       // 0..3: 64-cout slice
    const int l15 = lane & 15, lg = lane >> 4;
    const int bx = blockIdx.x;                     // b*28 + h-group
    const int b = bx / 28;
    const int h0 = (bx % 28) * 2;                  // 2 output rows per block

    char* bpriv = Bp + wn * 8192;                  // this wave's 2-slot ring
    const char* bwsrc = wt + wn * 4096 + lane * 16;
    const int bfoff = (lg * 16) ^ ((l15 & 3) << 4);  // B frag byte within row

    // ---- prologue: A (32KB); B stages 0,1 -> slots 0,1; S2 rows ----
    const char* agbase = xpi8 + (size_t)(b * 58 + h0) * 8192;
#pragma unroll
    for (int i = 0; i < 8; ++i)
        gload_lds16(agbase + i * 4096 + tid * 16, As + i * 4096 + tid * 16);
#pragma unroll
    for (int st = 0; st < 2; ++st)
#pragma unroll
        for (int i = 0; i < 4; ++i)
            gload_lds16(bwsrc + (size_t)st * 16384 + i * 1024,
                        bpriv + st * 4096 + i * 1024 + lane * 16);
    if (tid < 128) {
        int row = tid >> 6, m = tid & 63;
        int s = 0;
        if (m < 56) {
#pragma unroll
            for (int kh = 0; kh < 3; ++kh)
#pragma unroll
                for (int kw = 0; kw < 3; ++kw)
                    s += colsum[(b * 58 + h0 + row + kh) * 64 + m + kw];
        }
        s2row[row][m] = s;
    }

    i32x4 acc[4][8];                               // [fn][fm]: row=cout, col=m
#pragma unroll
    for (int i = 0; i < 4; ++i)
#pragma unroll
        for (int j = 0; j < 8; ++j)
            acc[i][j] = (i32x4){0, 0, 0, 0};

    __syncthreads();                               // the ONLY barrier (drains all)

#pragma unroll
    for (int s = 0; s < 18; ++s) {                 // 9 taps x 2 cin-halves
        const int kh = (s >> 1) / 3, kw = (s >> 1) % 3, ch = s & 1;
        // 1) read frags: stage s resident (s<2: barrier; s>=2: prior vmcnt(4))
        const char* bslot = bpriv + (s & 1) * 4096;
        i32x4 bfr[4];
#pragma unroll
        for (int fn = 0; fn < 4; ++fn) {
            int nn = fn * 16 + l15;
            bfr[fn] = *(const i32x4*)(bslot + nn * 64 + bfoff);
        }
        i32x4 afr[8];
#pragma unroll
        for (int fm = 0; fm < 8; ++fm) {
            int rowoff = fm >> 2;                  // 0..1: output row
            int wv = (fm & 3) * 16 + l15 + kw;
            int wc = wv > 63 ? 63 : wv;            // clamped lanes are dead outputs
            int ab = (rowoff + kh) * 8192 + wc * 128 +
                     ((ch * 64 + lg * 16) ^ ((wc & 7) << 4));
            afr[fm] = *(const i32x4*)(As + ab);
        }
        // 2) slot s&1 reads done -> 3) reuse it for stage s+2
        if (s < 16) {
            asm volatile("s_waitcnt lgkmcnt(0)" ::: "memory");
#pragma unroll
            for (int i = 0; i < 4; ++i)
                gload_lds16(bwsrc + (size_t)(s + 2) * 16384 + i * 1024,
                            bpriv + (s & 1) * 4096 + i * 1024 + lane * 16);
        }
        // 4) counted wait: stage s+1 landed (1-step slack; never drains early)
        if (s < 16)       asm volatile("s_waitcnt vmcnt(4)" ::: "memory");
        else if (s == 16) asm volatile("s_waitcnt vmcnt(0)" ::: "memory");
        // 5) MFMA burst (swapped operands: D[row=cout][col=m])
#pragma unroll
        for (int fn = 0; fn < 4; ++fn)
#pragma unroll
            for (int fm = 0; fm < 8; ++fm)
                acc[fn][fm] = __builtin_amdgcn_mfma_i32_16x16x64_i8(
                    bfr[fn], afr[fm], acc[fn][fm], 0, 0, 0);
    }

    // ---- epilogue: +correction, requantize, ReLU, round; coalesced in m ----
    const float Mv  = *Mp;
    const float yzv = *yzp;
    const float CWf = 128.0f - *wzp;               // (128 - w_zero)
#pragma unroll
    for (int fn = 0; fn < 4; ++fn) {
#pragma unroll
        for (int reg = 0; reg < 4; ++reg) {
            const int cout = wn * 64 + fn * 16 + lg * 4 + reg;
            const float bv = bias[cout];
#pragma unroll
            for (int fm = 0; fm < 8; ++fm) {
                const int row = fm >> 2;
                const int m = (fm & 3) * 16 + l15; // lane-contiguous
                if (m < 56) {
                    const size_t rowb =
                        ((size_t)(b * 256 + cout) * 56 + h0 + row) * 56;
                    float af = (float)acc[fn][fm][reg] +
                               CWf * (float)s2row[row][m];
                    float v = (af + bv) * Mv + yzv;
                    v = fmaxf(v, yzv);
                    out[rowb + m] = rintf(v);
                }
            }
        }
    }
}

extern "C" void kernel_launch(void* const* d_in, const int* in_sizes, int n_in,
                              void* d_out, int out_size, void* d_ws, size_t ws_size,
                              hipStream_t stream) {
    const float* x    = (const float*)d_in[0];
    const float* w    = (const float*)d_in[1];
    const float* bias = (const float*)d_in[2];
    const float* Mp   = (const float*)d_in[3];
    const float* xzp  = (const float*)d_in[4];
    const float* wzp  = (const float*)d_in[5];
    const float* yzp  = (const float*)d_in[6];
    float* out = (float*)d_out;

    char* wt     = (char*)d_ws;                          // 288 KB
    char* xpi8   = wt + WTI8_BYTES;                      // 15.2 MB
    int*  colsum = (int*)(xpi8 + XPI8_BYTES);            // 475 KB

    wprep_kernel<<<72, 256, 0, stream>>>(w, wt);
    xprep_kernel<<<32 * 58, 256, 0, stream>>>(x, xzp, xpi8, colsum);
    conv_kernel<<<32 * 28, 256, 0, stream>>>(wt, xpi8, colsum, bias, Mp, wzp, yzp, out);
}